// Round 6
// baseline (28.020 us; speedup 1.0000x reference)
//
#include <hip/hip_runtime.h>

#define Bn 4
#define Mn 100
#define Dn 128
#define BS 18   // floats per box record

// ---------------- K0: prep — box geometry for all B*M boxes + zero accumulators
__global__ __launch_bounds__(256) void prep_kernel(
    const float* __restrict__ boxes,
    float* __restrict__ bws,          // Bn*Mn*BS floats
    float* __restrict__ gz)           // gsum|gcnt: 2*Bn*Mn floats
{
    const int t = blockIdx.x * 256 + threadIdx.x;   // 0..511
    for (int i = t; i < 2 * Bn * Mn; i += 512) gz[i] = 0.0f;
    if (t >= Bn * Mn) return;

    const float* bx = boxes + (size_t)t * 7;
    float cx = bx[0], cy = bx[1];
    float l = bx[3], w = bx[4], yaw = bx[6];
    const float DIMS0 = 51.2f + 51.2f;
    const float cellw = DIMS0 / 256.0f;
    float rl = fminf(fmaxf(cellw / l, 1.0f), 6.0f);
    float rw = fminf(fmaxf(cellw / w, 1.0f), 6.0f);
    float el = __fmul_rn(l, rl);
    float ew = __fmul_rn(w, rw);
    float c = cosf(yaw), s = sinf(yaw);
    const float nx[4] = {-0.5f, -0.5f, 0.5f, 0.5f};
    const float ny[4] = {-0.5f, 0.5f, 0.5f, -0.5f};
    float px[4], py[4];
    #pragma unroll
    for (int k = 0; k < 4; k++) {
        float ox = __fmul_rn(el, nx[k]);
        float oy = __fmul_rn(ew, ny[k]);
        float rx = __fadd_rn(__fmul_rn(ox, c), __fmul_rn(oy, s));
        float ry = __fadd_rn(__fmul_rn(-ox, s), __fmul_rn(oy, c));
        px[k] = __fadd_rn(rx, cx);
        py[k] = __fadd_rn(ry, cy);
    }
    float* o = bws + (size_t)t * BS;
    #pragma unroll
    for (int k = 0; k < 4; k++) { o[k * 2] = px[k]; o[k * 2 + 1] = py[k]; }
    #pragma unroll
    for (int k = 0; k < 4; k++) {
        o[8 + k * 2]     = __fsub_rn(px[(k + 1) & 3], px[k]);
        o[8 + k * 2 + 1] = __fsub_rn(py[(k + 1) & 3], py[k]);
    }
    o[16] = cy;
    o[17] = 0.5f * sqrtf(el * el + ew * ew) + 0.01f;  // conservative prune radius
}

// ---------------- K1: fused flag + quarter-gather. 4 blocks per (b,y) row.
__global__ __launch_bounds__(256) void fused_kernel(
    const float* __restrict__ atten,
    const float* __restrict__ bws,
    float* __restrict__ gsum, float* __restrict__ gcnt)
{
    __shared__ float sb[Mn * BS];
    __shared__ int   am[Mn];
    __shared__ int   wcnt[4], wbase[4];
    __shared__ int   nactS, nflag;
    __shared__ int   clist[256];
    __shared__ float ssum[Mn], scnt[Mn];

    const int row = blockIdx.x >> 2;        // 0..1023 = b*256+y
    const int q   = blockIdx.x & 3;
    const int b   = row >> 8;
    const int y   = row & 255;
    const int tx  = threadIdx.x;

    // load this scene's geometry (L2 broadcast across the 1024 blocks of the scene)
    for (int i = tx; i < Mn * BS; i += 256) sb[i] = bws[b * Mn * BS + i];
    if (tx == 0) nflag = 0;
    if (tx < Mn) { ssum[tx] = 0.0f; scnt[tx] = 0.0f; }
    __syncthreads();

    const float DIMS0 = 51.2f + 51.2f;
    float gy = __fadd_rn(__fmul_rn((y + 0.5f) * (1.0f / 256.0f), DIMS0), -51.2f);

    // y-band test (order-preserving active-box index list)
    bool act = false;
    if (tx < Mn)
        act = fabsf(gy - sb[tx * BS + 16]) <= sb[tx * BS + 17];
    unsigned long long mb = __ballot(act);
    int wid = tx >> 6;
    if ((tx & 63) == 0) wcnt[wid] = __popcll(mb);
    __syncthreads();
    if (tx == 0) {
        wbase[0] = 0;
        wbase[1] = wcnt[0];
        wbase[2] = wcnt[0] + wcnt[1];
        wbase[3] = wbase[2] + wcnt[2];
        nactS    = wbase[3] + wcnt[3];
    }
    __syncthreads();
    const int nact = nactS;
    if (nact == 0) return;                   // block-uniform
    if (act) {
        int slot = wbase[wid] + __popcll(mb & ((1ull << (tx & 63)) - 1ull));
        am[slot] = tx;
    }
    __syncthreads();

    // parity scan over active boxes (broadcast LDS reads; exact verified arithmetic)
    float gx = __fadd_rn(__fmul_rn((tx + 0.5f) * (1.0f / 256.0f), DIMS0), -51.2f);
    int flag = -1;
    for (int j = 0; j < nact; j++) {
        const int m = am[j];
        const float* o = &sb[m * BS];
        bool ge = true, le = true;
        #pragma unroll
        for (int k = 0; k < 4; k++) {
            float dx = __fsub_rn(gx, o[k * 2]);
            float dy = __fsub_rn(gy, o[k * 2 + 1]);
            float cr = __fsub_rn(__fmul_rn(o[8 + k * 2], dy),
                                 __fmul_rn(o[8 + k * 2 + 1], dx));
            ge = ge && (cr >= 0.0f);
            le = le && (cr <= 0.0f);
        }
        if (ge || le) flag = (flag == -1) ? m : -1;
    }
    if (flag >= 0) {
        int idx = atomicAdd(&nflag, 1);
        clist[idx] = (flag << 8) | tx;       // m (7b) | x (8b)
    }
    __syncthreads();
    const int n = nflag;

    // quarter-gather: 32 lane-groups across the row's 4 blocks, 2-way unrolled
    const int gg   = (q << 3) + (tx >> 5);   // 0..31
    const int lane = tx & 31;
    const size_t rowbase = (size_t)row << 8;
    for (int j = gg; j < n; j += 64) {
        int e0 = clist[j];
        int j1 = j + 32;
        bool h1 = j1 < n;
        int e1 = h1 ? clist[j1] : e0;
        const float4* p0 = reinterpret_cast<const float4*>(
            atten + (rowbase + (e0 & 255)) * Dn) + lane;
        const float4* p1 = reinterpret_cast<const float4*>(
            atten + (rowbase + (e1 & 255)) * Dn) + lane;
        float4 a0 = *p0;
        float4 a1 = *p1;
        float s0 = a0.x + a0.y + a0.z + a0.w;
        float q0 = a0.x * a0.x + a0.y * a0.y + a0.z * a0.z + a0.w * a0.w;
        float s1 = a1.x + a1.y + a1.z + a1.w;
        float q1 = a1.x * a1.x + a1.y * a1.y + a1.z * a1.z + a1.w * a1.w;
        #pragma unroll
        for (int d = 16; d; d >>= 1) {
            s0 += __shfl_xor(s0, d);
            q0 += __shfl_xor(q0, d);
            s1 += __shfl_xor(s1, d);
            q1 += __shfl_xor(q1, d);
        }
        if (lane == 0) {
            float v0 = (q0 - s0 * s0 * (1.0f / 128.0f)) * (1.0f / 127.0f);
            atomicAdd(&ssum[e0 >> 8], v0);
            atomicAdd(&scnt[e0 >> 8], 1.0f);
            if (h1) {
                float v1 = (q1 - s1 * s1 * (1.0f / 128.0f)) * (1.0f / 127.0f);
                atomicAdd(&ssum[e1 >> 8], v1);
                atomicAdd(&scnt[e1 >> 8], 1.0f);
            }
        }
    }
    __syncthreads();
    if (tx < Mn && scnt[tx] > 0.0f) {
        atomicAdd(&gsum[b * Mn + tx], ssum[tx]);
        atomicAdd(&gcnt[b * Mn + tx], scnt[tx]);
    }
}

// ---------------- K2: finalize scalar loss (1 block; verified pattern)
__global__ __launch_bounds__(512) void final_kernel(const float* __restrict__ gsum,
                                                    const float* __restrict__ gcnt,
                                                    float* __restrict__ out) {
    __shared__ float sl[8], sn[8];
    int t = threadIdx.x;
    float loss = 0.0f, num = 0.0f;
    if (t < Bn * Mn) {
        float c = gcnt[t];
        if (c > 0.0f) {
            loss = -(gsum[t] / fmaxf(c, 1.0f));
            num = 1.0f;
        }
    }
    #pragma unroll
    for (int m = 32; m; m >>= 1) {
        loss += __shfl_xor(loss, m);
        num  += __shfl_xor(num, m);
    }
    if ((t & 63) == 0) { sl[t >> 6] = loss; sn[t >> 6] = num; }
    __syncthreads();
    if (t == 0) {
        float L = 0.0f, N = 0.0f;
        #pragma unroll
        for (int i = 0; i < 8; i++) { L += sl[i]; N += sn[i]; }
        out[0] = L / fmaxf(N, 1.0f);
    }
}

extern "C" void kernel_launch(void* const* d_in, const int* in_sizes, int n_in,
                              void* d_out, int out_size, void* d_ws, size_t ws_size,
                              hipStream_t stream) {
    const float* atten = (const float*)d_in[0];
    const float* boxes = (const float*)d_in[1];
    float* out = (float*)d_out;

    // ws layout: gsum[400] | gcnt[400] | bws @ +4096 (400*18 floats = 28.8 KB)
    float* gsum = (float*)d_ws;
    float* gcnt = gsum + Bn * Mn;
    float* bws  = (float*)((char*)d_ws + 4096);

    prep_kernel<<<2, 256, 0, stream>>>(boxes, bws, gsum);
    fused_kernel<<<4 * Bn * 256, 256, 0, stream>>>(atten, bws, gsum, gcnt);
    final_kernel<<<1, 512, 0, stream>>>(gsum, gcnt, out);
}

// Round 7
// 22.742 us; speedup vs baseline: 1.2321x; 1.2321x over previous
//
#include <hip/hip_runtime.h>

#define Bn 4
#define Mn 100
#define Dn 128

// ---------------- K1: flags -> deterministic per-row cell lists (verbatim R5, verified)
__global__ __launch_bounds__(256) void flag_kernel(
    const float* __restrict__ boxes,
    unsigned int* __restrict__ rowcnt,
    unsigned int* __restrict__ cells,
    float* __restrict__ gz)            // gsum|gcnt region: 2*Bn*Mn floats
{
    __shared__ float abox[Mn * 18];
    __shared__ int   am[Mn];
    __shared__ int   wcnt[4], wbase[4];
    __shared__ int   nactS, nflag;
    __shared__ int   clist[256];

    const int b  = blockIdx.x >> 8;
    const int y  = blockIdx.x & 255;
    const int tx = threadIdx.x;

    // zero the accumulator region (visible to gather via kernel boundary)
    if (blockIdx.x < 2 * Bn * Mn && tx == 0) gz[blockIdx.x] = 0.0f;
    if (tx == 0) nflag = 0;

    const float DIMS0 = 51.2f + 51.2f;
    float gy = __fadd_rn(__fmul_rn((y + 0.5f) * (1.0f / 256.0f), DIMS0), -51.2f);

    // geometry in registers (exact arithmetic of the verified rounds)
    float px[4], py[4], ex[4], ey[4];
    bool act = false;
    if (tx < Mn) {
        const float* bx = boxes + (size_t)(b * Mn + tx) * 7;
        float cx = bx[0], cy = bx[1];
        float l = bx[3], w = bx[4], yaw = bx[6];
        const float cellw = DIMS0 / 256.0f;
        float rl = fminf(fmaxf(cellw / l, 1.0f), 6.0f);
        float rw = fminf(fmaxf(cellw / w, 1.0f), 6.0f);
        float el = __fmul_rn(l, rl);
        float ew = __fmul_rn(w, rw);
        float c = cosf(yaw), s = sinf(yaw);
        const float nx[4] = {-0.5f, -0.5f, 0.5f, 0.5f};
        const float ny[4] = {-0.5f, 0.5f, 0.5f, -0.5f};
        #pragma unroll
        for (int k = 0; k < 4; k++) {
            float ox = __fmul_rn(el, nx[k]);
            float oy = __fmul_rn(ew, ny[k]);
            float rx = __fadd_rn(__fmul_rn(ox, c), __fmul_rn(oy, s));
            float ry = __fadd_rn(__fmul_rn(-ox, s), __fmul_rn(oy, c));
            px[k] = __fadd_rn(rx, cx);
            py[k] = __fadd_rn(ry, cy);
        }
        #pragma unroll
        for (int k = 0; k < 4; k++) {
            ex[k] = __fsub_rn(px[(k + 1) & 3], px[k]);
            ey[k] = __fsub_rn(py[(k + 1) & 3], py[k]);
        }
        float r = 0.5f * sqrtf(el * el + ew * ew) + 0.01f;
        act = fabsf(gy - cy) <= r;       // conservative y-band
    }

    // order-preserving compaction of y-active boxes (m order preserved)
    unsigned long long mb = __ballot(act);
    int wid = tx >> 6;
    if ((tx & 63) == 0) wcnt[wid] = __popcll(mb);
    __syncthreads();
    if (tx == 0) {
        wbase[0] = 0;
        wbase[1] = wcnt[0];
        wbase[2] = wcnt[0] + wcnt[1];
        wbase[3] = wbase[2] + wcnt[2];
        nactS    = wbase[3] + wcnt[3];
    }
    __syncthreads();
    const int nact = nactS;
    if (nact == 0) {                      // no box touches this row
        if (tx == 0) rowcnt[blockIdx.x] = 0;
        return;
    }
    if (act) {
        int slot = wbase[wid] + __popcll(mb & ((1ull << (tx & 63)) - 1ull));
        float* o = abox + slot * 18;
        #pragma unroll
        for (int k = 0; k < 4; k++) {
            o[k * 2] = px[k];  o[k * 2 + 1] = py[k];
            o[8 + k * 2] = ex[k]; o[8 + k * 2 + 1] = ey[k];
        }
        am[slot] = tx;
    }
    __syncthreads();

    // per-cell parity scan over the ~5 y-active boxes (broadcast LDS reads)
    float gx = __fadd_rn(__fmul_rn((tx + 0.5f) * (1.0f / 256.0f), DIMS0), -51.2f);
    int flag = -1;
    for (int j = 0; j < nact; j++) {
        const float* o = &abox[j * 18];
        bool ge = true, le = true;
        #pragma unroll
        for (int k = 0; k < 4; k++) {
            float dx = __fsub_rn(gx, o[k * 2]);
            float dy = __fsub_rn(gy, o[k * 2 + 1]);
            float cr = __fsub_rn(__fmul_rn(o[8 + k * 2], dy),
                                 __fmul_rn(o[8 + k * 2 + 1], dx));
            ge = ge && (cr >= 0.0f);
            le = le && (cr <= 0.0f);
        }
        if (ge || le) flag = (flag == -1) ? am[j] : -1;
    }

    if (flag >= 0) {
        int idx = atomicAdd(&nflag, 1);
        clist[idx] = (flag << 8) | tx;    // m (7b) | x (8b)
    }
    __syncthreads();
    if (tx == 0) rowcnt[blockIdx.x] = nflag;
    for (int i = tx; i < nflag; i += 256)
        cells[(blockIdx.x << 8) + i] = clist[i];
}

// ---------------- K2: sparse variance gather, 4 blocks/row (32 groups) + 2-way unroll
__global__ __launch_bounds__(256) void gather_kernel(
    const float* __restrict__ atten,
    const unsigned int* __restrict__ rowcnt,
    const unsigned int* __restrict__ cells,
    float* __restrict__ gsum, float* __restrict__ gcnt)
{
    __shared__ float ssum[Mn], scnt[Mn];
    const int tx  = threadIdx.x;
    const int row = blockIdx.x >> 2;        // 0..1023 = b*256+y
    const int q   = blockIdx.x & 3;
    const int b   = row >> 8;
    const unsigned int n = rowcnt[row];

    if (tx < Mn) { ssum[tx] = 0.0f; scnt[tx] = 0.0f; }
    if (n == 0) return;                      // block-uniform
    __syncthreads();

    const int g    = (q << 3) + (tx >> 5);   // 0..31
    const int lane = tx & 31;
    const unsigned int base = (unsigned int)row << 8;
    const size_t rowbase = (size_t)base;
    for (unsigned int j = g; j < n; j += 64) {
        unsigned int e0 = cells[base + j];
        unsigned int j1 = j + 32;
        bool h1 = j1 < n;
        unsigned int e1 = h1 ? cells[base + j1] : e0;
        const float4* p0 = reinterpret_cast<const float4*>(
            atten + (rowbase + (e0 & 255)) * Dn) + lane;
        const float4* p1 = reinterpret_cast<const float4*>(
            atten + (rowbase + (e1 & 255)) * Dn) + lane;
        float4 a0 = *p0;
        float4 a1 = *p1;
        float s0 = a0.x + a0.y + a0.z + a0.w;
        float q0 = a0.x * a0.x + a0.y * a0.y + a0.z * a0.z + a0.w * a0.w;
        float s1 = a1.x + a1.y + a1.z + a1.w;
        float q1 = a1.x * a1.x + a1.y * a1.y + a1.z * a1.z + a1.w * a1.w;
        #pragma unroll
        for (int d = 16; d; d >>= 1) {
            s0 += __shfl_xor(s0, d);
            q0 += __shfl_xor(q0, d);
            s1 += __shfl_xor(s1, d);
            q1 += __shfl_xor(q1, d);
        }
        if (lane == 0) {
            float v0 = (q0 - s0 * s0 * (1.0f / 128.0f)) * (1.0f / 127.0f);
            atomicAdd(&ssum[e0 >> 8], v0);
            atomicAdd(&scnt[e0 >> 8], 1.0f);
            if (h1) {
                float v1 = (q1 - s1 * s1 * (1.0f / 128.0f)) * (1.0f / 127.0f);
                atomicAdd(&ssum[e1 >> 8], v1);
                atomicAdd(&scnt[e1 >> 8], 1.0f);
            }
        }
    }
    __syncthreads();
    if (tx < Mn && scnt[tx] > 0.0f) {
        atomicAdd(&gsum[b * Mn + tx], ssum[tx]);
        atomicAdd(&gcnt[b * Mn + tx], scnt[tx]);
    }
}

// ---------------- K3: finalize scalar loss (1 block; verified pattern)
__global__ __launch_bounds__(512) void final_kernel(const float* __restrict__ gsum,
                                                    const float* __restrict__ gcnt,
                                                    float* __restrict__ out) {
    __shared__ float sl[8], sn[8];
    int t = threadIdx.x;
    float loss = 0.0f, num = 0.0f;
    if (t < Bn * Mn) {
        float c = gcnt[t];
        if (c > 0.0f) {
            loss = -(gsum[t] / fmaxf(c, 1.0f));
            num = 1.0f;
        }
    }
    #pragma unroll
    for (int m = 32; m; m >>= 1) {
        loss += __shfl_xor(loss, m);
        num  += __shfl_xor(num, m);
    }
    if ((t & 63) == 0) { sl[t >> 6] = loss; sn[t >> 6] = num; }
    __syncthreads();
    if (t == 0) {
        float L = 0.0f, N = 0.0f;
        #pragma unroll
        for (int i = 0; i < 8; i++) { L += sl[i]; N += sn[i]; }
        out[0] = L / fmaxf(N, 1.0f);
    }
}

extern "C" void kernel_launch(void* const* d_in, const int* in_sizes, int n_in,
                              void* d_out, int out_size, void* d_ws, size_t ws_size,
                              hipStream_t stream) {
    const float* atten = (const float*)d_in[0];
    const float* boxes = (const float*)d_in[1];
    float* out = (float*)d_out;

    // ws layout: gsum[400] | gcnt[400] | rowcnt[1024] @+3200 | cells @+8192 (1 MB)
    float* gsum = (float*)d_ws;
    float* gcnt = gsum + Bn * Mn;
    unsigned int* rowcnt = (unsigned int*)((char*)d_ws + 3200);
    unsigned int* cells  = (unsigned int*)((char*)d_ws + 8192);

    flag_kernel<<<Bn * 256, 256, 0, stream>>>(boxes, rowcnt, cells, gsum);
    gather_kernel<<<4 * Bn * 256, 256, 0, stream>>>(atten, rowcnt, cells, gsum, gcnt);
    final_kernel<<<1, 512, 0, stream>>>(gsum, gcnt, out);
}